// Round 1
// baseline (107.573 us; speedup 1.0000x reference)
//
#include <hip/hip_runtime.h>
#include <hip/hip_bf16.h>
#include <float.h>

// ChamferLoss: preds [B,N,3] f32, gts [B,N,3] f32 -> scalar f32
// loss = sum_j min_i ||gt_i - pred_j||^2  +  sum_i min_j ||gt_i - pred_j||^2
//
// Trick: d^2 = ||a||^2 + (||b||^2 - 2 a.b). Precompute ||b||^2 per tile point
// (stored as .w of an LDS float4) and (-2a) + ||a||^2 per thread. Inner loop:
// 1 ds_read_b128 (uniform/broadcast) + 3 FMA + 1 min per pair.

#define TILE 2048
#define BLK  256

__global__ __launch_bounds__(BLK) void chamfer_kernel(
    const float* __restrict__ preds, const float* __restrict__ gts,
    float* __restrict__ out, int N) {

    const int dir = blockIdx.z;           // 0: query=preds, target=gts ; 1: swapped
    const int b   = blockIdx.y;
    const int tid = threadIdx.x;
    const int idx = blockIdx.x * BLK + tid;

    const float* Aq = dir == 0 ? preds : gts;   // query points (one per thread)
    const float* Bt = dir == 0 ? gts   : preds; // target points (min over)

    const float* Ab = Aq + (size_t)b * N * 3;
    const float* Bb = Bt + (size_t)b * N * 3;

    __shared__ float4 lds[TILE];
    __shared__ float  psum[BLK / 64];

    // Per-thread query point
    float a2x = 0.f, a2y = 0.f, a2z = 0.f, an = 0.f;
    const bool valid = idx < N;
    if (valid) {
        float ax = Ab[idx * 3 + 0];
        float ay = Ab[idx * 3 + 1];
        float az = Ab[idx * 3 + 2];
        a2x = -2.f * ax; a2y = -2.f * ay; a2z = -2.f * az;
        an  = ax * ax + ay * ay + az * az;
    }

    float m0 = FLT_MAX, m1 = FLT_MAX, m2 = FLT_MAX, m3 = FLT_MAX;

    for (int t = 0; t < N; t += TILE) {
        // Stage TILE target points into LDS with precomputed squared norm.
        for (int k = tid; k < TILE; k += BLK) {
            int j = t + k;
            float x = Bb[j * 3 + 0];
            float y = Bb[j * 3 + 1];
            float z = Bb[j * 3 + 2];
            lds[k] = make_float4(x, y, z, x * x + y * y + z * z);
        }
        __syncthreads();

        #pragma unroll 4
        for (int k = 0; k < TILE; k += 4) {
            float4 p0 = lds[k + 0];
            float4 p1 = lds[k + 1];
            float4 p2 = lds[k + 2];
            float4 p3 = lds[k + 3];
            m0 = fminf(m0, fmaf(a2x, p0.x, fmaf(a2y, p0.y, fmaf(a2z, p0.z, p0.w))));
            m1 = fminf(m1, fmaf(a2x, p1.x, fmaf(a2y, p1.y, fmaf(a2z, p1.z, p1.w))));
            m2 = fminf(m2, fmaf(a2x, p2.x, fmaf(a2y, p2.y, fmaf(a2z, p2.z, p2.w))));
            m3 = fminf(m3, fmaf(a2x, p3.x, fmaf(a2y, p3.y, fmaf(a2z, p3.z, p3.w))));
        }
        __syncthreads();
    }

    float m = fminf(fminf(m0, m1), fminf(m2, m3)) + an;
    float contrib = valid ? m : 0.f;

    // Wave64 reduce
    for (int off = 32; off > 0; off >>= 1)
        contrib += __shfl_down(contrib, off, 64);
    if ((tid & 63) == 0) psum[tid >> 6] = contrib;
    __syncthreads();
    if (tid == 0) {
        float s = 0.f;
        for (int w = 0; w < BLK / 64; ++w) s += psum[w];
        atomicAdd(out, s);
    }
}

extern "C" void kernel_launch(void* const* d_in, const int* in_sizes, int n_in,
                              void* d_out, int out_size, void* d_ws, size_t ws_size,
                              hipStream_t stream) {
    const float* preds = (const float*)d_in[0];
    const float* gts   = (const float*)d_in[1];
    float* out = (float*)d_out;

    const int B = 4, D = 3;
    const int N = in_sizes[0] / (B * D);   // 8192

    hipMemsetAsync(out, 0, sizeof(float) * out_size, stream);

    dim3 grid((N + BLK - 1) / BLK, B, 2);
    dim3 block(BLK);
    chamfer_kernel<<<grid, block, 0, stream>>>(preds, gts, out, N);
}

// Round 2
// 75.580 us; speedup vs baseline: 1.4233x; 1.4233x over previous
//
#include <hip/hip_runtime.h>
#include <hip/hip_bf16.h>
#include <float.h>

// ChamferLoss: preds [B,N,3] f32, gts [B,N,3] f32 -> scalar f32
// loss = sum_j min_i ||gt_i - pred_j||^2  +  sum_i min_j ||gt_i - pred_j||^2
//
// R2: split target dim into SEG segments for full occupancy (32 waves/CU).
// Partial mins combined via atomicMin on monotone-encoded float keys in d_ws;
// second kernel decodes + sums. Inner loop: 1 ds_read_b128 (broadcast) +
// 3 FMA per pair, 1 v_min3 per 2 pairs.

#define BLK  256
#define SEG  8

__device__ __forceinline__ unsigned int enc_f32(float f) {
    unsigned int u = __float_as_uint(f);
    return (u & 0x80000000u) ? ~u : (u | 0x80000000u);
}
__device__ __forceinline__ float dec_f32(unsigned int k) {
    return __uint_as_float((k & 0x80000000u) ? (k & 0x7FFFFFFFu) : ~k);
}

__global__ __launch_bounds__(BLK) void chamfer_min_kernel(
    const float* __restrict__ preds, const float* __restrict__ gts,
    unsigned int* __restrict__ keys, int N) {

    const int seg = blockIdx.z % SEG;
    const int dir = blockIdx.z / SEG;     // 0: query=preds ; 1: query=gts
    const int b   = blockIdx.y;
    const int tid = threadIdx.x;
    const int idx = blockIdx.x * BLK + tid;
    const int TT  = N / SEG;              // targets per segment

    const float* Aq = dir == 0 ? preds : gts;
    const float* Bt = dir == 0 ? gts   : preds;
    const float* Ab = Aq + (size_t)b * N * 3;
    const float* Bb = Bt + (size_t)b * N * 3;

    __shared__ float4 lds[1024];          // TT <= 1024 (N=8192, SEG=8)

    // Per-thread query point
    float a2x = 0.f, a2y = 0.f, a2z = 0.f, an = 0.f;
    const bool valid = idx < N;
    if (valid) {
        float ax = Ab[idx * 3 + 0];
        float ay = Ab[idx * 3 + 1];
        float az = Ab[idx * 3 + 2];
        a2x = -2.f * ax; a2y = -2.f * ay; a2z = -2.f * az;
        an  = ax * ax + ay * ay + az * az;
    }

    // Stage this segment's targets with precomputed ||b||^2
    for (int k = tid; k < TT; k += BLK) {
        int j = seg * TT + k;
        float x = Bb[j * 3 + 0];
        float y = Bb[j * 3 + 1];
        float z = Bb[j * 3 + 2];
        lds[k] = make_float4(x, y, z, x * x + y * y + z * z);
    }
    __syncthreads();

    float m0 = FLT_MAX, m1 = FLT_MAX, m2 = FLT_MAX, m3 = FLT_MAX;

    #pragma unroll 2
    for (int k = 0; k < TT; k += 8) {
        float4 p0 = lds[k + 0];
        float4 p1 = lds[k + 1];
        float4 p2 = lds[k + 2];
        float4 p3 = lds[k + 3];
        float4 p4 = lds[k + 4];
        float4 p5 = lds[k + 5];
        float4 p6 = lds[k + 6];
        float4 p7 = lds[k + 7];
        float d0 = fmaf(a2x, p0.x, fmaf(a2y, p0.y, fmaf(a2z, p0.z, p0.w)));
        float d1 = fmaf(a2x, p1.x, fmaf(a2y, p1.y, fmaf(a2z, p1.z, p1.w)));
        float d2 = fmaf(a2x, p2.x, fmaf(a2y, p2.y, fmaf(a2z, p2.z, p2.w)));
        float d3 = fmaf(a2x, p3.x, fmaf(a2y, p3.y, fmaf(a2z, p3.z, p3.w)));
        float d4 = fmaf(a2x, p4.x, fmaf(a2y, p4.y, fmaf(a2z, p4.z, p4.w)));
        float d5 = fmaf(a2x, p5.x, fmaf(a2y, p5.y, fmaf(a2z, p5.z, p5.w)));
        float d6 = fmaf(a2x, p6.x, fmaf(a2y, p6.y, fmaf(a2z, p6.z, p6.w)));
        float d7 = fmaf(a2x, p7.x, fmaf(a2y, p7.y, fmaf(a2z, p7.z, p7.w)));
        m0 = fminf(fminf(d0, d1), m0);   // hope: v_min3_f32
        m1 = fminf(fminf(d2, d3), m1);
        m2 = fminf(fminf(d4, d5), m2);
        m3 = fminf(fminf(d6, d7), m3);
    }

    if (valid) {
        float m = fminf(fminf(m0, m1), fminf(m2, m3)) + an;
        unsigned int* slot = keys + ((size_t)(dir * 4 + b) * N + idx);
        atomicMin(slot, enc_f32(m));
    }
}

__global__ __launch_bounds__(BLK) void chamfer_sum_kernel(
    const unsigned int* __restrict__ keys, float* __restrict__ out, int M) {

    __shared__ float psum[BLK / 64];
    int gid = blockIdx.x * BLK + threadIdx.x;
    int stride = gridDim.x * BLK;
    float s = 0.f;
    for (int i = gid; i < M; i += stride) s += dec_f32(keys[i]);
    for (int off = 32; off > 0; off >>= 1) s += __shfl_down(s, off, 64);
    if ((threadIdx.x & 63) == 0) psum[threadIdx.x >> 6] = s;
    __syncthreads();
    if (threadIdx.x == 0) {
        float t = 0.f;
        for (int w = 0; w < BLK / 64; ++w) t += psum[w];
        atomicAdd(out, t);
    }
}

// ---- Fallback (R1 single-kernel version) if ws too small ----
__global__ __launch_bounds__(BLK) void chamfer_kernel_fb(
    const float* __restrict__ preds, const float* __restrict__ gts,
    float* __restrict__ out, int N) {
    const int dir = blockIdx.z;
    const int b   = blockIdx.y;
    const int tid = threadIdx.x;
    const int idx = blockIdx.x * BLK + tid;
    const float* Aq = dir == 0 ? preds : gts;
    const float* Bt = dir == 0 ? gts   : preds;
    const float* Ab = Aq + (size_t)b * N * 3;
    const float* Bb = Bt + (size_t)b * N * 3;
    __shared__ float4 lds[2048];
    __shared__ float  psum[BLK / 64];
    float a2x = 0.f, a2y = 0.f, a2z = 0.f, an = 0.f;
    const bool valid = idx < N;
    if (valid) {
        float ax = Ab[idx * 3], ay = Ab[idx * 3 + 1], az = Ab[idx * 3 + 2];
        a2x = -2.f * ax; a2y = -2.f * ay; a2z = -2.f * az;
        an  = ax * ax + ay * ay + az * az;
    }
    float m0 = FLT_MAX, m1 = FLT_MAX, m2 = FLT_MAX, m3 = FLT_MAX;
    for (int t = 0; t < N; t += 2048) {
        for (int k = tid; k < 2048; k += BLK) {
            int j = t + k;
            float x = Bb[j * 3], y = Bb[j * 3 + 1], z = Bb[j * 3 + 2];
            lds[k] = make_float4(x, y, z, x * x + y * y + z * z);
        }
        __syncthreads();
        #pragma unroll 4
        for (int k = 0; k < 2048; k += 4) {
            float4 p0 = lds[k], p1 = lds[k + 1], p2 = lds[k + 2], p3 = lds[k + 3];
            m0 = fminf(m0, fmaf(a2x, p0.x, fmaf(a2y, p0.y, fmaf(a2z, p0.z, p0.w))));
            m1 = fminf(m1, fmaf(a2x, p1.x, fmaf(a2y, p1.y, fmaf(a2z, p1.z, p1.w))));
            m2 = fminf(m2, fmaf(a2x, p2.x, fmaf(a2y, p2.y, fmaf(a2z, p2.z, p2.w))));
            m3 = fminf(m3, fmaf(a2x, p3.x, fmaf(a2y, p3.y, fmaf(a2z, p3.z, p3.w))));
        }
        __syncthreads();
    }
    float m = fminf(fminf(m0, m1), fminf(m2, m3)) + an;
    float contrib = valid ? m : 0.f;
    for (int off = 32; off > 0; off >>= 1) contrib += __shfl_down(contrib, off, 64);
    if ((tid & 63) == 0) psum[tid >> 6] = contrib;
    __syncthreads();
    if (tid == 0) {
        float s = 0.f;
        for (int w = 0; w < BLK / 64; ++w) s += psum[w];
        atomicAdd(out, s);
    }
}

extern "C" void kernel_launch(void* const* d_in, const int* in_sizes, int n_in,
                              void* d_out, int out_size, void* d_ws, size_t ws_size,
                              hipStream_t stream) {
    const float* preds = (const float*)d_in[0];
    const float* gts   = (const float*)d_in[1];
    float* out = (float*)d_out;

    const int B = 4, D = 3;
    const int N = in_sizes[0] / (B * D);   // 8192

    hipMemsetAsync(out, 0, sizeof(float) * out_size, stream);

    const size_t keys_bytes = (size_t)2 * B * N * sizeof(unsigned int); // 256 KB
    if (ws_size >= keys_bytes && (N % SEG) == 0 && (N / SEG) <= 1024) {
        unsigned int* keys = (unsigned int*)d_ws;
        // 0xFF bytes -> max key (decodes to NaN but every slot gets written)
        hipMemsetAsync(keys, 0xFF, keys_bytes, stream);
        dim3 grid((N + BLK - 1) / BLK, B, 2 * SEG);
        chamfer_min_kernel<<<grid, BLK, 0, stream>>>(preds, gts, keys, N);
        int M = 2 * B * N;
        chamfer_sum_kernel<<<64, BLK, 0, stream>>>(keys, out, M);
    } else {
        dim3 grid((N + BLK - 1) / BLK, B, 2);
        chamfer_kernel_fb<<<grid, BLK, 0, stream>>>(preds, gts, out, N);
    }
}

// Round 3
// 56.493 us; speedup vs baseline: 1.9042x; 1.3379x over previous
//
#include <hip/hip_runtime.h>
#include <hip/hip_bf16.h>
#include <float.h>

// ChamferLoss: preds [B,N,3] f32, gts [B,N,3] f32 -> scalar f32
// R3: register-block Q=4 queries per thread so each broadcast ds_read_b128
// serves 4 query points (LDS instrs/pair /4). VALU/pair = 3 FMA + 0.5 min3
// (min3 forced via inline asm). SEG=16 target segments keep 16 waves/CU.
// Partial mins combined via atomicMin on monotone-encoded floats in d_ws.

#define BLK  256
#define SEG  16
#define Q    4

__device__ __forceinline__ unsigned int enc_f32(float f) {
    unsigned int u = __float_as_uint(f);
    return (u & 0x80000000u) ? ~u : (u | 0x80000000u);
}
__device__ __forceinline__ float dec_f32(unsigned int k) {
    return __uint_as_float((k & 0x80000000u) ? (k & 0x7FFFFFFFu) : ~k);
}
__device__ __forceinline__ float min3f(float a, float b, float c) {
    float r;
    asm("v_min3_f32 %0, %1, %2, %3" : "=v"(r) : "v"(a), "v"(b), "v"(c));
    return r;
}

__global__ __launch_bounds__(BLK) void chamfer_min_kernel(
    const float* __restrict__ preds, const float* __restrict__ gts,
    unsigned int* __restrict__ keys, int N) {

    const int seg = blockIdx.z % SEG;
    const int dir = blockIdx.z / SEG;     // 0: query=preds ; 1: query=gts
    const int b   = blockIdx.y;
    const int tid = threadIdx.x;
    const int TT  = N / SEG;              // 512 targets per segment

    const float* Aq = dir == 0 ? preds : gts;
    const float* Bt = dir == 0 ? gts   : preds;
    const float* Ab = Aq + (size_t)b * N * 3;
    const float* Bb = Bt + (size_t)b * N * 3;

    __shared__ float4 sh[512];

    // Q queries per thread, strided by BLK for coalesced-ish loads
    const int qbase = blockIdx.x * (BLK * Q);
    float a2x[Q], a2y[Q], a2z[Q], an[Q];
    bool  vq[Q];
    #pragma unroll
    for (int q = 0; q < Q; ++q) {
        int idx = qbase + q * BLK + tid;
        vq[q] = idx < N;
        int ci = vq[q] ? idx : 0;
        float ax = Ab[ci * 3 + 0];
        float ay = Ab[ci * 3 + 1];
        float az = Ab[ci * 3 + 2];
        a2x[q] = -2.f * ax; a2y[q] = -2.f * ay; a2z[q] = -2.f * az;
        an[q]  = ax * ax + ay * ay + az * az;
    }

    // Stage this segment's targets with precomputed ||b||^2
    for (int k = tid; k < TT; k += BLK) {
        int j = seg * TT + k;
        float x = Bb[j * 3 + 0];
        float y = Bb[j * 3 + 1];
        float z = Bb[j * 3 + 2];
        sh[k] = make_float4(x, y, z, x * x + y * y + z * z);
    }
    __syncthreads();

    float m[Q];
    #pragma unroll
    for (int q = 0; q < Q; ++q) m[q] = FLT_MAX;

    #pragma unroll 2
    for (int k = 0; k < TT; k += 4) {
        float4 p0 = sh[k + 0];
        float4 p1 = sh[k + 1];
        float4 p2 = sh[k + 2];
        float4 p3 = sh[k + 3];
        #pragma unroll
        for (int q = 0; q < Q; ++q) {
            float d0 = fmaf(a2x[q], p0.x, fmaf(a2y[q], p0.y, fmaf(a2z[q], p0.z, p0.w)));
            float d1 = fmaf(a2x[q], p1.x, fmaf(a2y[q], p1.y, fmaf(a2z[q], p1.z, p1.w)));
            float d2 = fmaf(a2x[q], p2.x, fmaf(a2y[q], p2.y, fmaf(a2z[q], p2.z, p2.w)));
            float d3 = fmaf(a2x[q], p3.x, fmaf(a2y[q], p3.y, fmaf(a2z[q], p3.z, p3.w)));
            m[q] = min3f(d0, d1, m[q]);
            m[q] = min3f(d2, d3, m[q]);
        }
    }

    #pragma unroll
    for (int q = 0; q < Q; ++q) {
        if (vq[q]) {
            int idx = qbase + q * BLK + tid;
            unsigned int* slot = keys + ((size_t)(dir * 4 + b) * N + idx);
            atomicMin(slot, enc_f32(m[q] + an[q]));
        }
    }
}

__global__ __launch_bounds__(BLK) void chamfer_sum_kernel(
    const unsigned int* __restrict__ keys, float* __restrict__ out, int M) {

    __shared__ float psum[BLK / 64];
    int gid = blockIdx.x * BLK + threadIdx.x;
    int stride = gridDim.x * BLK;
    float s = 0.f;
    for (int i = gid; i < M; i += stride) s += dec_f32(keys[i]);
    for (int off = 32; off > 0; off >>= 1) s += __shfl_down(s, off, 64);
    if ((threadIdx.x & 63) == 0) psum[threadIdx.x >> 6] = s;
    __syncthreads();
    if (threadIdx.x == 0) {
        float t = 0.f;
        for (int w = 0; w < BLK / 64; ++w) t += psum[w];
        atomicAdd(out, t);
    }
}

// ---- Fallback (single-kernel) if ws too small / odd shapes ----
__global__ __launch_bounds__(BLK) void chamfer_kernel_fb(
    const float* __restrict__ preds, const float* __restrict__ gts,
    float* __restrict__ out, int N) {
    const int dir = blockIdx.z;
    const int b   = blockIdx.y;
    const int tid = threadIdx.x;
    const int idx = blockIdx.x * BLK + tid;
    const float* Aq = dir == 0 ? preds : gts;
    const float* Bt = dir == 0 ? gts   : preds;
    const float* Ab = Aq + (size_t)b * N * 3;
    const float* Bb = Bt + (size_t)b * N * 3;
    __shared__ float4 lds[2048];
    __shared__ float  psum[BLK / 64];
    float a2x = 0.f, a2y = 0.f, a2z = 0.f, an = 0.f;
    const bool valid = idx < N;
    if (valid) {
        float ax = Ab[idx * 3], ay = Ab[idx * 3 + 1], az = Ab[idx * 3 + 2];
        a2x = -2.f * ax; a2y = -2.f * ay; a2z = -2.f * az;
        an  = ax * ax + ay * ay + az * az;
    }
    float m0 = FLT_MAX, m1 = FLT_MAX, m2 = FLT_MAX, m3 = FLT_MAX;
    for (int t = 0; t < N; t += 2048) {
        int lim = min(2048, N - t);
        for (int k = tid; k < lim; k += BLK) {
            int j = t + k;
            float x = Bb[j * 3], y = Bb[j * 3 + 1], z = Bb[j * 3 + 2];
            lds[k] = make_float4(x, y, z, x * x + y * y + z * z);
        }
        __syncthreads();
        for (int k = 0; k + 3 < lim; k += 4) {
            float4 p0 = lds[k], p1 = lds[k + 1], p2 = lds[k + 2], p3 = lds[k + 3];
            m0 = fminf(m0, fmaf(a2x, p0.x, fmaf(a2y, p0.y, fmaf(a2z, p0.z, p0.w))));
            m1 = fminf(m1, fmaf(a2x, p1.x, fmaf(a2y, p1.y, fmaf(a2z, p1.z, p1.w))));
            m2 = fminf(m2, fmaf(a2x, p2.x, fmaf(a2y, p2.y, fmaf(a2z, p2.z, p2.w))));
            m3 = fminf(m3, fmaf(a2x, p3.x, fmaf(a2y, p3.y, fmaf(a2z, p3.z, p3.w))));
        }
        for (int k = lim & ~3; k < lim; ++k) {
            float4 p0 = lds[k];
            m0 = fminf(m0, fmaf(a2x, p0.x, fmaf(a2y, p0.y, fmaf(a2z, p0.z, p0.w))));
        }
        __syncthreads();
    }
    float m = fminf(fminf(m0, m1), fminf(m2, m3)) + an;
    float contrib = valid ? m : 0.f;
    for (int off = 32; off > 0; off >>= 1) contrib += __shfl_down(contrib, off, 64);
    if ((tid & 63) == 0) psum[tid >> 6] = contrib;
    __syncthreads();
    if (tid == 0) {
        float s = 0.f;
        for (int w = 0; w < BLK / 64; ++w) s += psum[w];
        atomicAdd(out, s);
    }
}

extern "C" void kernel_launch(void* const* d_in, const int* in_sizes, int n_in,
                              void* d_out, int out_size, void* d_ws, size_t ws_size,
                              hipStream_t stream) {
    const float* preds = (const float*)d_in[0];
    const float* gts   = (const float*)d_in[1];
    float* out = (float*)d_out;

    const int B = 4, D = 3;
    const int N = in_sizes[0] / (B * D);   // 8192

    hipMemsetAsync(out, 0, sizeof(float) * out_size, stream);

    const size_t keys_bytes = (size_t)2 * B * N * sizeof(unsigned int); // 256 KB
    if (ws_size >= keys_bytes && (N % SEG) == 0 && (N / SEG) <= 512) {
        unsigned int* keys = (unsigned int*)d_ws;
        hipMemsetAsync(keys, 0xFF, keys_bytes, stream);
        dim3 grid((N + BLK * Q - 1) / (BLK * Q), B, 2 * SEG);
        chamfer_min_kernel<<<grid, BLK, 0, stream>>>(preds, gts, keys, N);
        int M = 2 * B * N;
        chamfer_sum_kernel<<<64, BLK, 0, stream>>>(keys, out, M);
    } else {
        dim3 grid((N + BLK - 1) / BLK, B, 2);
        chamfer_kernel_fb<<<grid, BLK, 0, stream>>>(preds, gts, out, N);
    }
}